// Round 7
// baseline (424.345 us; speedup 1.0000x reference)
//
#include <hip/hip_runtime.h>
#include <hip/hip_bf16.h>

typedef __bf16 bf16x8 __attribute__((ext_vector_type(8)));
typedef __bf16 bf16x4 __attribute__((ext_vector_type(4)));
typedef float  floatx4 __attribute__((ext_vector_type(4)));

#define SH  2097152ll  // per-batch plane: 2048*1024
#define SS  4194304ll  // per-batch score plane: 2048*2048

// Async global->LDS, 16 B per lane. LDS dest is wave-uniform base + lane*16.
#define GLOAD16(gp, lp)                                                        \
  __builtin_amdgcn_global_load_lds(                                            \
      (const __attribute__((address_space(1))) void*)(gp),                     \
      (__attribute__((address_space(3))) void*)(lp), 16, 0, 0)

// ---------------------------------------------------------------------------
// Verified bf16 core (round 0/6): 128 x (NB*32) x BK64, 256 thr = 4 waves.
// 32 KB LDS -> 4-5 blocks/CU; cross-block MFMA/staging overlap is the
// mechanism (qkv 29.9% MfmaUtil at 6/CU vs 21-24% for all 1-block/CU
// schedule variants, rounds 1-4). LDS XOR swizzle: chunk c of row r at
// physical c^(r&7); staging lane loads global chunk (lane&7)^(lane>>3).
// SQ_LDS_BANK_CONFLICT == 0 measured.
// ---------------------------------------------------------------------------
template <int NB>
__device__ __forceinline__ void gemm_core(
    const __bf16* __restrict__ A, const __bf16* __restrict__ B,
    __bf16* As, __bf16* Bs, floatx4 (&acc)[4][NB],
    int m0, int n0, int Kd, int lda, int ldb, int tid) {
  const int lane = tid & 63;
  const int w    = tid >> 6;
  const int lo   = lane & 15;
  const int quad = lane >> 4;
  const int lrow  = lane >> 3;
  const int lcol8 = ((lane & 7) ^ lrow) * 8;

  const __bf16* aptr = A + (size_t)(m0 + w * 32 + lrow) * lda + lcol8;
  const __bf16* bptr = B + (size_t)(n0 + w * (NB * 8) + lrow) * ldb + lcol8;
  __bf16* asl = As + (w * 32) * 64;
  __bf16* bsl = Bs + (w * (NB * 8)) * 64;

  const int x7 = lo & 7;

  for (int kk = 0; kk < Kd; kk += 64) {
#pragma unroll
    for (int i = 0; i < 4; i++)
      GLOAD16(aptr + (size_t)(i * 8) * lda + kk, asl + i * 8 * 64);
#pragma unroll
    for (int i = 0; i < NB; i++)
      GLOAD16(bptr + (size_t)(i * 8) * ldb + kk, bsl + i * 8 * 64);
    __syncthreads();
#pragma unroll
    for (int kq = 0; kq < 2; kq++) {
      const int pq = ((kq * 4 + quad) ^ x7) * 8;
      bf16x8 af[4], bfq[NB];
#pragma unroll
      for (int mt = 0; mt < 4; mt++)
        af[mt] = *(const bf16x8*)&As[((w >> 1) * 64 + mt * 16 + lo) * 64 + pq];
#pragma unroll
      for (int nt = 0; nt < NB; nt++)
        bfq[nt] = *(const bf16x8*)
            &Bs[((w & 1) * (NB * 16) + nt * 16 + lo) * 64 + pq];
#pragma unroll
      for (int mt = 0; mt < 4; mt++)
#pragma unroll
        for (int nt = 0; nt < NB; nt++)
          acc[mt][nt] = __builtin_amdgcn_mfma_f32_16x16x32_bf16(af[mt], bfq[nt], acc[mt][nt], 0, 0, 0);
    }
    __syncthreads();
  }
}

#define GEMM_PRE(NB)                                                           \
  __shared__ __bf16 As[128 * 64];                                              \
  __shared__ __bf16 Bs[(NB) * 32 * 64];                                        \
  const int tid = threadIdx.x;                                                 \
  floatx4 acc[4][NB];                                                          \
  _Pragma("unroll") for (int mt = 0; mt < 4; mt++)                             \
      _Pragma("unroll") for (int nt = 0; nt < (NB); nt++)                      \
          acc[mt][nt] = (floatx4){0.f, 0.f, 0.f, 0.f};                         \
  const int lane = tid & 63, w = tid >> 6, lo = lane & 15, quad = lane >> 4;   \
  (void)lo; (void)quad;

// ---------------------------------------------------------------------------
// fp32-direct staging (prep weight-GEMMs): convert fp32 global -> swizzled
// bf16 LDS in registers. Same LDS layout as GLOAD16 staging.
// ---------------------------------------------------------------------------
__device__ __forceinline__ void stage_f32(const float* __restrict__ G,
                                          int row0, int kk, __bf16* Ls, int tid) {
  const int lane = tid & 63, w = tid >> 6;
  const int lrow = lane >> 3, lch = ((lane & 7) ^ lrow) * 8;
#pragma unroll
  for (int i = 0; i < 4; i++) {
    const float* p = G + (size_t)(row0 + w * 32 + i * 8 + lrow) * 1024 + kk + lch;
    float4 v0 = *(const float4*)p, v1 = *(const float4*)(p + 4);
    bf16x8 o;
    o[0] = (__bf16)v0.x; o[1] = (__bf16)v0.y; o[2] = (__bf16)v0.z; o[3] = (__bf16)v0.w;
    o[4] = (__bf16)v1.x; o[5] = (__bf16)v1.y; o[6] = (__bf16)v1.z; o[7] = (__bf16)v1.w;
    ((bf16x8*)Ls)[(w * 32 + i * 8) * 8 + lane] = o;
  }
}

// Transpose-stage: source G fp32 [m][e] row-major; tile = 128 e-rows x 64 m.
// Logical m-chunk c of row e written at physical chunk c^(e&7).
__device__ __forceinline__ void stage_f32_t(const float* __restrict__ G,
                                            int e0, int kk, __bf16* Ls, int tid) {
  const int e  = tid & 127;
  const int c2 = tid >> 7;   // 0..1
#pragma unroll
  for (int q = 0; q < 4; q++) {
    const int c = c2 * 4 + q;
    bf16x8 o;
#pragma unroll
    for (int i = 0; i < 8; i++)
      o[i] = (__bf16)G[(size_t)(kk + c * 8 + i) * 1024 + e0 + e];
    *(bf16x8*)((char*)Ls + e * 128 + ((c ^ (e & 7)) * 16)) = o;
  }
}

template <bool TA>
__device__ __forceinline__ void gemm_f32(
    const float* __restrict__ Ag, const float* __restrict__ Bg,
    __bf16* As, __bf16* Bs, floatx4 (&acc)[4][4], int m0, int n0, int tid) {
  const int lane = tid & 63, w = tid >> 6;
  const int lo = lane & 15, quad = lane >> 4;
  const int x7 = lo & 7;
  for (int kk = 0; kk < 1024; kk += 64) {
    if constexpr (TA) stage_f32_t(Ag, m0, kk, As, tid);
    else              stage_f32(Ag, m0, kk, As, tid);
    stage_f32(Bg, n0, kk, Bs, tid);
    __syncthreads();
#pragma unroll
    for (int kq = 0; kq < 2; kq++) {
      const int pq = ((kq * 4 + quad) ^ x7) * 8;
      bf16x8 af[4], bfq[4];
#pragma unroll
      for (int mt = 0; mt < 4; mt++)
        af[mt] = *(const bf16x8*)&As[((w >> 1) * 64 + mt * 16 + lo) * 64 + pq];
#pragma unroll
      for (int nt = 0; nt < 4; nt++)
        bfq[nt] = *(const bf16x8*)&Bs[((w & 1) * 64 + nt * 16 + lo) * 64 + pq];
#pragma unroll
      for (int mt = 0; mt < 4; mt++)
#pragma unroll
        for (int nt = 0; nt < 4; nt++)
          acc[mt][nt] = __builtin_amdgcn_mfma_f32_16x16x32_bf16(af[mt], bfq[nt], acc[mt][nt], 0, 0, 0);
    }
    __syncthreads();
  }
}

// ---------------------------------------------------------------------------
// PREP (everything weight/input-space), grid (16,16,6):
//  z=0    : X fp32 -> bf16; zero L (first 32 blocks).
//  z=1..4 : mask pack -> bitmask Pk (quarter per plane).
//  z=5    : weight GEMMs + vectors, all reading RAW fp32 inputs:
//     bid 0..63   : M2T = Wk @ Wq^T  (scores kernel: QK^T = X M2 X^T + ...)
//     bid 64..127 : MT  = (Wv @ Wo)^T  [A = Wo^T via transpose-stage]
//     bid 128..135: w1 = Wq@bk, w2 = Wk@bq   (bias cross-terms)
//     bid 136     : c0 = bq.bk
//     bid 137..144: bvWo = bv @ Wo
// ---------------------------------------------------------------------------
__global__ __launch_bounds__(256) void prep_k(
    const float* __restrict__ X, __bf16* __restrict__ Xb,
    const float* __restrict__ Wq, const float* __restrict__ Wk,
    const float* __restrict__ Wv, const float* __restrict__ Wo,
    const float* __restrict__ bq, const float* __restrict__ bk,
    const float* __restrict__ bv, __bf16* __restrict__ W2,
    float* __restrict__ w1, float* __restrict__ w2, float* __restrict__ c0,
    float* __restrict__ bvWo, float* __restrict__ L,
    const int* __restrict__ mask, unsigned* __restrict__ Pk) {
  __shared__ __bf16 As[128 * 64];
  __shared__ __bf16 Bs[128 * 64];
  const int z = blockIdx.z;
  const int tid = threadIdx.x;
  const int bid = blockIdx.y * 16 + blockIdx.x;  // 0..255
  if (z == 0) {
    if (bid < 32) L[bid * 256 + tid] = 0.f;
#pragma unroll
    for (int k = 0; k < 32; k++) {
      const size_t i = (size_t)(bid * 256 + tid) + (size_t)k * 65536;
      const float4 v = ((const float4*)X)[i];
      bf16x4 o;
      o[0] = (__bf16)v.x; o[1] = (__bf16)v.y; o[2] = (__bf16)v.z; o[3] = (__bf16)v.w;
      ((bf16x4*)Xb)[i] = o;
    }
    return;
  }
  if (z <= 4) {
    const int base = (z - 1) * 131072;  // u32 words per quarter
#pragma unroll
    for (int k = 0; k < 2; k++) {
      const int idx = base + bid * 512 + k * 256 + tid;
      const int4* m4 = (const int4*)(mask + (size_t)idx * 32);
      unsigned bits = 0;
#pragma unroll
      for (int q = 0; q < 8; q++) {
        int4 v = m4[q];
        bits |= (v.x != 0 ? 1u : 0u) << (q * 4);
        bits |= (v.y != 0 ? 1u : 0u) << (q * 4 + 1);
        bits |= (v.z != 0 ? 1u : 0u) << (q * 4 + 2);
        bits |= (v.w != 0 ? 1u : 0u) << (q * 4 + 3);
      }
      Pk[idx] = bits;
    }
    return;
  }
  // z == 5: weight-space work.
  if (bid < 128) {
    const bool m2 = bid < 64;
    const int t2 = m2 ? bid : bid - 64;
    const int m0 = (t2 >> 3) * 128, n0 = (t2 & 7) * 128;
    floatx4 acc[4][4];
#pragma unroll
    for (int mt = 0; mt < 4; mt++)
#pragma unroll
      for (int nt = 0; nt < 4; nt++) acc[mt][nt] = (floatx4){0.f, 0.f, 0.f, 0.f};
    if (m2) gemm_f32<false>(Wk, Wq, As, Bs, acc, m0, n0, tid);  // M2T=Wk@Wq^T
    else    gemm_f32<true>(Wo, Wv, As, Bs, acc, m0, n0, tid);   // MT[e][d]
    const int lane = tid & 63, w = tid >> 6, lo = lane & 15, quad = lane >> 4;
    const int rbase = m2 ? 0 : 1024;
#pragma unroll
    for (int mt = 0; mt < 4; mt++) {
      const int gr = m0 + (w >> 1) * 64 + mt * 16 + quad * 4;
#pragma unroll
      for (int nt = 0; nt < 4; nt++) {
        const int gc = n0 + (w & 1) * 64 + nt * 16 + lo;
#pragma unroll
        for (int r = 0; r < 4; r++)
          W2[(size_t)(rbase + gr + r) * 1024 + gc] = (__bf16)acc[mt][nt][r];
      }
    }
    return;
  }
  if (bid < 136) {  // w1, w2
    const int c = (bid - 128) * 128 + (tid >> 1);
    const int h = (tid & 1) * 512;
    const float* r1 = Wq + (size_t)c * 1024 + h;
    const float* r2 = Wk + (size_t)c * 1024 + h;
    float s1 = 0.f, s2 = 0.f;
    for (int k = 0; k < 512; k += 4) {
      float4 q4 = *(const float4*)(r1 + k);
      float4 k4 = *(const float4*)(r2 + k);
      s1 += q4.x * bk[h + k] + q4.y * bk[h + k + 1] + q4.z * bk[h + k + 2] + q4.w * bk[h + k + 3];
      s2 += k4.x * bq[h + k] + k4.y * bq[h + k + 1] + k4.z * bq[h + k + 2] + k4.w * bq[h + k + 3];
    }
    s1 += __shfl_xor(s1, 1);
    s2 += __shfl_xor(s2, 1);
    if ((tid & 1) == 0) { w1[c] = s1; w2[c] = s2; }
    return;
  }
  if (bid == 136) {  // c0 = bq.bk
    float s = 0.f;
    for (int e = tid; e < 1024; e += 256) s += bq[e] * bk[e];
#pragma unroll
    for (int d = 32; d >= 1; d >>= 1) s += __shfl_xor(s, d);
    float* red = (float*)As;
    if ((tid & 63) == 0) red[tid >> 6] = s;
    __syncthreads();
    if (tid == 0) c0[0] = red[0] + red[1] + red[2] + red[3];
    return;
  }
  if (bid < 145) {  // bvWo
    const int e = (bid - 137) * 128 + (tid >> 1);
    const int h = (tid & 1) * 512;
    float s = 0.f;
#pragma unroll 4
    for (int m = 0; m < 512; m++) s += bv[h + m] * Wo[(size_t)(h + m) * 1024 + e];
    s += __shfl_xor(s, 1);
    if ((tid & 1) == 0) bvWo[e] = s;
    return;
  }
}

// PROJ: C[8192 x 2048] = Xb @ W2^T. Chunk 0 (n<1024): T = X@M2 (plain store).
// Chunk 1: VWo = X@(WvWo) + bvWo, stored TRANSPOSED per batch VWoT[e][s].
// x==0 blocks also compute a = Xb@w1, b = Xb@w2 for their 128 rows.
// grid (16, 64), 256 thr.
__global__ __launch_bounds__(256) void proj_k(
    const __bf16* __restrict__ Xb, const __bf16* __restrict__ W2,
    const float* __restrict__ w1, const float* __restrict__ w2,
    const float* __restrict__ bvwo, __bf16* __restrict__ T,
    __bf16* __restrict__ VWoT, float* __restrict__ av, float* __restrict__ bg) {
  GEMM_PRE(4);
  const int m0 = blockIdx.y * 128, n0 = blockIdx.x * 128;
  gemm_core<4>(Xb, W2, As, Bs, acc, m0, n0, 1024, 1024, 1024, tid);
  if (n0 < 1024) {
#pragma unroll
    for (int mt = 0; mt < 4; mt++) {
      const int gmb = m0 + (w >> 1) * 64 + mt * 16 + quad * 4;
#pragma unroll
      for (int nt = 0; nt < 4; nt++) {
        const int gn = n0 + (w & 1) * 64 + nt * 16 + lo;
#pragma unroll
        for (int r = 0; r < 4; r++)
          T[(size_t)(gmb + r) * 1024 + gn] = (__bf16)acc[mt][nt][r];
      }
    }
    if (blockIdx.x == 0) {  // a,b for rows m0..m0+127
      const int row = m0 + (tid >> 1);
      const int h = (tid & 1) * 512;
      const __bf16* xr = Xb + (size_t)row * 1024 + h;
      float s1 = 0.f, s2 = 0.f;
      for (int k = 0; k < 512; k += 8) {
        bf16x8 xv = *(const bf16x8*)(xr + k);
#pragma unroll
        for (int j = 0; j < 8; j++) {
          const float xf = (float)xv[j];
          s1 += xf * w1[h + k + j];
          s2 += xf * w2[h + k + j];
        }
      }
      s1 += __shfl_xor(s1, 1);
      s2 += __shfl_xor(s2, 1);
      if ((tid & 1) == 0) { av[row] = s1; bg[row] = s2; }
    }
  } else {
    const int bz = m0 >> 11;
    const int sb = (m0 & 2047) + (w >> 1) * 64;
    const int n0l = n0 - 1024;
#pragma unroll
    for (int mt = 0; mt < 4; mt++) {
      const int sl = sb + mt * 16 + quad * 4;
#pragma unroll
      for (int nt = 0; nt < 4; nt++) {
        const int e = n0l + (w & 1) * 64 + nt * 16 + lo;
        const float b_ = bvwo[e];
        bf16x4 pk;
#pragma unroll
        for (int r = 0; r < 4; r++) pk[r] = (__bf16)(acc[mt][nt][r] + b_);
        *(bf16x4*)(VWoT + (size_t)bz * SH + (size_t)e * 2048 + sl) = pk;
      }
    }
  }
}

// MID: scores = T@Xb^T + a_i + b_j + c0; E = exp(maskbit?1e-20:scores/32)
// bf16 + rowsum atomics into L. grid (256,1,4) = 4 blocks/CU. XCD decode.
__global__ __launch_bounds__(256) void mid_k(
    const __bf16* __restrict__ T, const __bf16* __restrict__ Xb,
    __bf16* __restrict__ E, const unsigned* __restrict__ Pk,
    float* __restrict__ L, const float* __restrict__ av,
    const float* __restrict__ bg, const float* __restrict__ c0) {
  GEMM_PRE(4);
  const int bz = blockIdx.z;
  const int sid = blockIdx.x;
  const int xcd = sid & 7, kk = sid >> 3;
  const int m0 = ((xcd >> 1) * 4 + (kk >> 3)) * 128;
  const int n0 = ((xcd & 1) * 8 + (kk & 7)) * 128;
  gemm_core<4>(T + bz * SH, Xb + bz * SH, As, Bs, acc,
               m0, n0, 1024, 1024, 1024, tid);
  const unsigned* Pb = Pk + (size_t)bz * 131072;
  const float c0f = c0[0];
  const float* ab = av + (size_t)bz * 2048;
  const float* bb = bg + (size_t)bz * 2048;
  float bn[4];
#pragma unroll
  for (int nt = 0; nt < 4; nt++)
    bn[nt] = bb[n0 + (w & 1) * 64 + nt * 16 + lo] + c0f;
#pragma unroll
  for (int mt = 0; mt < 4; mt++) {
    const int gmb = m0 + (w >> 1) * 64 + mt * 16 + quad * 4;
#pragma unroll
    for (int r = 0; r < 4; r++) {
      const int gm = gmb + r;
      const float avr = ab[gm];
      float rowpart = 0.f;
#pragma unroll
      for (int nt = 0; nt < 4; nt++) {
        const int gn = n0 + (w & 1) * 64 + nt * 16 + lo;
        const unsigned wd = Pb[(size_t)gm * 64 + (gn >> 5)];
        float s = (acc[mt][nt][r] + avr + bn[nt]) * 0.03125f;
        if ((wd >> (gn & 31)) & 1u) s = 1e-20f;
        const float e = __expf(s);
        rowpart += e;
        E[(size_t)bz * SS + (size_t)gm * 2048 + gn] = (__bf16)e;
      }
      rowpart += __shfl_xor(rowpart, 1);
      rowpart += __shfl_xor(rowpart, 2);
      rowpart += __shfl_xor(rowpart, 4);
      rowpart += __shfl_xor(rowpart, 8);
      if (lo == 0) atomicAdd(&L[(size_t)bz * 2048 + gm], rowpart);
    }
  }
}

// CTX/OUT fused: out = (E @ VWoT^T) / L + bo -> fp32. 128x64 tiles (NB=2),
// grid (256,1,4) = 4 blocks/CU, XCD patch decode. (round-6 verified)
__global__ __launch_bounds__(256) void ctx_k(
    const __bf16* __restrict__ E, const __bf16* __restrict__ VWoT,
    const float* __restrict__ L, const float* __restrict__ bo,
    float* __restrict__ out) {
  GEMM_PRE(2);
  const int bz = blockIdx.z;
  const int sid = blockIdx.x;
  const int xcd = sid & 7, k = sid >> 3;
  const int p  = k >> 3;
  const int q  = k & 7;
  const int py = (xcd >> 2) * 4 + p;
  const int px = xcd & 3;
  const int m0 = (py * 2 + (q >> 2)) * 128;
  const int n0 = (px * 4 + (q & 3)) * 64;
  gemm_core<2>(E + (size_t)bz * SS, VWoT + (size_t)bz * SH, As, Bs, acc,
               m0, n0, 2048, 2048, 2048, tid);
#pragma unroll
  for (int mt = 0; mt < 4; mt++) {
    const int gmb = m0 + (w >> 1) * 64 + mt * 16 + quad * 4;
#pragma unroll
    for (int nt = 0; nt < 2; nt++) {
      const int gn = n0 + (w & 1) * 32 + nt * 16 + lo;
      const float bo_ = bo[gn];
#pragma unroll
      for (int r = 0; r < 4; r++) {
        const int gm = gmb + r;
        const float inv = 1.0f / L[(size_t)bz * 2048 + gm];
        out[((size_t)bz * 2048 + gm) * 1024 + gn] = acc[mt][nt][r] * inv + bo_;
      }
    }
  }
}

extern "C" void kernel_launch(void* const* d_in, const int* in_sizes, int n_in,
                              void* d_out, int out_size, void* d_ws, size_t ws_size,
                              hipStream_t stream) {
  (void)in_sizes; (void)n_in; (void)out_size; (void)ws_size;
  const int H = 1024;

  const float* X   = (const float*)d_in[0];
  const int*   msk = (const int*)d_in[1];
  const float* Wq  = (const float*)d_in[2];
  const float* bq  = (const float*)d_in[3];
  const float* Wk  = (const float*)d_in[4];
  const float* bk  = (const float*)d_in[5];
  const float* Wv  = (const float*)d_in[6];
  const float* bv  = (const float*)d_in[7];
  const float* Wo  = (const float*)d_in[8];
  const float* bo  = (const float*)d_in[9];
  float* out = (float*)d_out;

  // Workspace (~91 MB):
  //   Xb[16.8M] W2[4.2M: M2T|MT] T[16.8M] VWoT[16.8M] E[33.6M]
  //   L[32K] a[32K] b[32K] w1/w2[8K] c0 bvWo[4K] Pk[2.1M]
  char* ws = (char*)d_ws;
  __bf16* Xb   = (__bf16*)ws;
  __bf16* W2   = Xb + (size_t)8192 * H;
  __bf16* Tb   = W2 + (size_t)2048 * H;
  __bf16* VWoT = Tb + (size_t)8192 * H;
  __bf16* E    = VWoT + (size_t)4 * H * 2048;
  float*  L    = (float*)(E + (size_t)4 * SS);
  float*  av   = L + 8192;
  float*  bg   = av + 8192;
  float*  w1   = bg + 8192;
  float*  w2   = w1 + 1024;
  float*  c0   = w2 + 1024;
  float*  bvWo = c0 + 4;
  unsigned* Pk = (unsigned*)(bvWo + 1024);

  dim3 blk(256);

  prep_k<<<dim3(16, 16, 6), blk, 0, stream>>>(X, Xb, Wq, Wk, Wv, Wo, bq, bk, bv,
                                              W2, w1, w2, c0, bvWo, L, msk, Pk);
  proj_k<<<dim3(16, 64), blk, 0, stream>>>(Xb, W2, w1, w2, bvWo, Tb, VWoT, av, bg);
  mid_k<<<dim3(256, 1, 4), blk, 0, stream>>>(Tb, Xb, E, Pk, L, av, bg, c0);
  ctx_k<<<dim3(256, 1, 4), blk, 0, stream>>>(E, VWoT, L, bo, out);
}

// Round 8
// 363.094 us; speedup vs baseline: 1.1687x; 1.1687x over previous
//
#include <hip/hip_runtime.h>
#include <hip/hip_bf16.h>

typedef __bf16 bf16x8 __attribute__((ext_vector_type(8)));
typedef __bf16 bf16x4 __attribute__((ext_vector_type(4)));
typedef float  floatx4 __attribute__((ext_vector_type(4)));

#define SH  2097152ll  // per-batch plane: 2048*1024
#define MSH 8388608ll  // full Q/K plane: 8192*1024
#define SS  4194304ll  // per-batch score plane: 2048*2048

// Async global->LDS, 16 B per lane. LDS dest is wave-uniform base + lane*16.
#define GLOAD16(gp, lp)                                                        \
  __builtin_amdgcn_global_load_lds(                                            \
      (const __attribute__((address_space(1))) void*)(gp),                     \
      (__attribute__((address_space(3))) void*)(lp), 16, 0, 0)

// ---------------------------------------------------------------------------
// Verified bf16 core (rounds 0/5/6): 128 x (NB*32) x BK64, 256 thr = 4 waves.
// 32 KB LDS -> 4-5 blocks/CU; cross-block MFMA/staging overlap is the
// mechanism (qkv 29.9% MfmaUtil at 6/CU vs 21-24% for all 1-block/CU
// schedule variants, rounds 1-4; round-7's proj confirmed again: any
// structure change that breaks residency/balance loses). LDS XOR swizzle:
// chunk c of row r at physical c^(r&7); staging lane loads global chunk
// (lane&7)^(lane>>3). SQ_LDS_BANK_CONFLICT == 0 measured.
// ---------------------------------------------------------------------------
template <int NB>
__device__ __forceinline__ void gemm_core(
    const __bf16* __restrict__ A, const __bf16* __restrict__ B,
    __bf16* As, __bf16* Bs, floatx4 (&acc)[4][NB],
    int m0, int n0, int Kd, int lda, int ldb, int tid) {
  const int lane = tid & 63;
  const int w    = tid >> 6;
  const int lo   = lane & 15;
  const int quad = lane >> 4;
  const int lrow  = lane >> 3;
  const int lcol8 = ((lane & 7) ^ lrow) * 8;

  const __bf16* aptr = A + (size_t)(m0 + w * 32 + lrow) * lda + lcol8;
  const __bf16* bptr = B + (size_t)(n0 + w * (NB * 8) + lrow) * ldb + lcol8;
  __bf16* asl = As + (w * 32) * 64;
  __bf16* bsl = Bs + (w * (NB * 8)) * 64;

  const int x7 = lo & 7;

  for (int kk = 0; kk < Kd; kk += 64) {
#pragma unroll
    for (int i = 0; i < 4; i++)
      GLOAD16(aptr + (size_t)(i * 8) * lda + kk, asl + i * 8 * 64);
#pragma unroll
    for (int i = 0; i < NB; i++)
      GLOAD16(bptr + (size_t)(i * 8) * ldb + kk, bsl + i * 8 * 64);
    __syncthreads();
#pragma unroll
    for (int kq = 0; kq < 2; kq++) {
      const int pq = ((kq * 4 + quad) ^ x7) * 8;
      bf16x8 af[4], bfq[NB];
#pragma unroll
      for (int mt = 0; mt < 4; mt++)
        af[mt] = *(const bf16x8*)&As[((w >> 1) * 64 + mt * 16 + lo) * 64 + pq];
#pragma unroll
      for (int nt = 0; nt < NB; nt++)
        bfq[nt] = *(const bf16x8*)
            &Bs[((w & 1) * (NB * 16) + nt * 16 + lo) * 64 + pq];
#pragma unroll
      for (int mt = 0; mt < 4; mt++)
#pragma unroll
        for (int nt = 0; nt < NB; nt++)
          acc[mt][nt] = __builtin_amdgcn_mfma_f32_16x16x32_bf16(af[mt], bfq[nt], acc[mt][nt], 0, 0, 0);
    }
    __syncthreads();
  }
}

#define GEMM_PRE(NB)                                                           \
  __shared__ __bf16 As[128 * 64];                                              \
  __shared__ __bf16 Bs[(NB) * 32 * 64];                                        \
  const int tid = threadIdx.x;                                                 \
  floatx4 acc[4][NB];                                                          \
  _Pragma("unroll") for (int mt = 0; mt < 4; mt++)                             \
      _Pragma("unroll") for (int nt = 0; nt < (NB); nt++)                      \
          acc[mt][nt] = (floatx4){0.f, 0.f, 0.f, 0.f};                         \
  const int lane = tid & 63, w = tid >> 6, lo = lane & 15, quad = lane >> 4;   \
  (void)lo; (void)quad;

// ---------------------------------------------------------------------------
// fp32-direct staging (prep MT GEMM): convert fp32 global -> swizzled bf16
// LDS in registers. Same LDS layout as GLOAD16 staging. (round-7 verified)
// ---------------------------------------------------------------------------
__device__ __forceinline__ void stage_f32(const float* __restrict__ G,
                                          int row0, int kk, __bf16* Ls, int tid) {
  const int lane = tid & 63, w = tid >> 6;
  const int lrow = lane >> 3, lch = ((lane & 7) ^ lrow) * 8;
#pragma unroll
  for (int i = 0; i < 4; i++) {
    const float* p = G + (size_t)(row0 + w * 32 + i * 8 + lrow) * 1024 + kk + lch;
    float4 v0 = *(const float4*)p, v1 = *(const float4*)(p + 4);
    bf16x8 o;
    o[0] = (__bf16)v0.x; o[1] = (__bf16)v0.y; o[2] = (__bf16)v0.z; o[3] = (__bf16)v0.w;
    o[4] = (__bf16)v1.x; o[5] = (__bf16)v1.y; o[6] = (__bf16)v1.z; o[7] = (__bf16)v1.w;
    ((bf16x8*)Ls)[(w * 32 + i * 8) * 8 + lane] = o;
  }
}

// Transpose-stage: source G fp32 [k][e] row-major; tile = 128 e-rows x 64 k.
// Logical k-chunk c of row e written at physical chunk c^(e&7).
__device__ __forceinline__ void stage_f32_t(const float* __restrict__ G,
                                            int e0, int kk, __bf16* Ls, int tid) {
  const int e  = tid & 127;
  const int c2 = tid >> 7;   // 0..1
#pragma unroll
  for (int q = 0; q < 4; q++) {
    const int c = c2 * 4 + q;
    bf16x8 o;
#pragma unroll
    for (int i = 0; i < 8; i++)
      o[i] = (__bf16)G[(size_t)(kk + c * 8 + i) * 1024 + e0 + e];
    *(bf16x8*)((char*)Ls + e * 128 + ((c ^ (e & 7)) * 16)) = o;
  }
}

// C[m][n] = sum_k A^T-staged[m][k] * B[n][k]  (A from fp32 cols, B fp32 rows)
__device__ __forceinline__ void gemm_f32t(
    const float* __restrict__ Ag, const float* __restrict__ Bg,
    __bf16* As, __bf16* Bs, floatx4 (&acc)[4][4], int m0, int n0, int tid) {
  const int lane = tid & 63, w = tid >> 6;
  const int lo = lane & 15, quad = lane >> 4;
  const int x7 = lo & 7;
  for (int kk = 0; kk < 1024; kk += 64) {
    stage_f32_t(Ag, m0, kk, As, tid);
    stage_f32(Bg, n0, kk, Bs, tid);
    __syncthreads();
#pragma unroll
    for (int kq = 0; kq < 2; kq++) {
      const int pq = ((kq * 4 + quad) ^ x7) * 8;
      bf16x8 af[4], bfq[4];
#pragma unroll
      for (int mt = 0; mt < 4; mt++)
        af[mt] = *(const bf16x8*)&As[((w >> 1) * 64 + mt * 16 + lo) * 64 + pq];
#pragma unroll
      for (int nt = 0; nt < 4; nt++)
        bfq[nt] = *(const bf16x8*)&Bs[((w & 1) * 64 + nt * 16 + lo) * 64 + pq];
#pragma unroll
      for (int mt = 0; mt < 4; mt++)
#pragma unroll
        for (int nt = 0; nt < 4; nt++)
          acc[mt][nt] = __builtin_amdgcn_mfma_f32_16x16x32_bf16(af[mt], bfq[nt], acc[mt][nt], 0, 0, 0);
    }
    __syncthreads();
  }
}

// ---------------------------------------------------------------------------
// PREP, grid (16,16,8):
//  z=0,1  : transpose+convert Wq,Wk (fp32 K x N) -> bf16 N x K plane of Wt.
//  z=2    : X fp32 -> bf16; zero L (first 32 blocks).
//  z=3..6 : mask pack -> bitmask Pk (quarter per plane).
//  z=7    : bid 0..63  : MTb[e][d] = (Wv@Wo)[d][e] from RAW fp32 (fp32-direct
//                        staging; replaces the round-6 wvwo_k straggler
//                        launch -- hides under the 1280 memory-bound blocks).
//           bid 64..71 : bvWo = bv @ Wo.
// ---------------------------------------------------------------------------
__global__ __launch_bounds__(256) void prep_k(
    const float* __restrict__ X, __bf16* __restrict__ Xb,
    const float* __restrict__ Wq, const float* __restrict__ Wk,
    const float* __restrict__ Wv, const float* __restrict__ Wo,
    const float* __restrict__ bv, __bf16* __restrict__ Wt,
    __bf16* __restrict__ MTb, float* __restrict__ bvWo,
    float* __restrict__ L, const int* __restrict__ mask,
    unsigned* __restrict__ Pk) {
  __shared__ __bf16 As[128 * 64];
  __shared__ __bf16 Bs[128 * 64];
  const int z = blockIdx.z;
  const int tid = threadIdx.x;
  const int bid = blockIdx.y * 16 + blockIdx.x;  // 0..255
  if (z == 2) {
    if (bid < 32) L[bid * 256 + tid] = 0.f;
#pragma unroll
    for (int k = 0; k < 32; k++) {
      const size_t i = (size_t)(bid * 256 + tid) + (size_t)k * 65536;
      const float4 v = ((const float4*)X)[i];
      bf16x4 o;
      o[0] = (__bf16)v.x; o[1] = (__bf16)v.y; o[2] = (__bf16)v.z; o[3] = (__bf16)v.w;
      ((bf16x4*)Xb)[i] = o;
    }
    return;
  }
  if (z >= 3 && z <= 6) {
    const int base = (z - 3) * 131072;  // u32 words per quarter
#pragma unroll
    for (int k = 0; k < 2; k++) {
      const int idx = base + bid * 512 + k * 256 + tid;
      const int4* m4 = (const int4*)(mask + (size_t)idx * 32);
      unsigned bits = 0;
#pragma unroll
      for (int q = 0; q < 8; q++) {
        int4 v = m4[q];
        bits |= (v.x != 0 ? 1u : 0u) << (q * 4);
        bits |= (v.y != 0 ? 1u : 0u) << (q * 4 + 1);
        bits |= (v.z != 0 ? 1u : 0u) << (q * 4 + 2);
        bits |= (v.w != 0 ? 1u : 0u) << (q * 4 + 3);
      }
      Pk[idx] = bits;
    }
    return;
  }
  if (z == 7) {
    if (bid < 64) {  // MT tiles
      const int m0 = (bid >> 3) * 128, n0 = (bid & 7) * 128;
      floatx4 acc[4][4];
#pragma unroll
      for (int mt = 0; mt < 4; mt++)
#pragma unroll
        for (int nt = 0; nt < 4; nt++) acc[mt][nt] = (floatx4){0.f, 0.f, 0.f, 0.f};
      gemm_f32t(Wo, Wv, As, Bs, acc, m0, n0, tid);  // MT[e][d]
      const int lane = tid & 63, w = tid >> 6, lo = lane & 15, quad = lane >> 4;
#pragma unroll
      for (int mt = 0; mt < 4; mt++) {
        const int ge = m0 + (w >> 1) * 64 + mt * 16 + quad * 4;
#pragma unroll
        for (int nt = 0; nt < 4; nt++) {
          const int gd = n0 + (w & 1) * 64 + nt * 16 + lo;
#pragma unroll
          for (int r = 0; r < 4; r++)
            MTb[(size_t)(ge + r) * 1024 + gd] = (__bf16)acc[mt][nt][r];
        }
      }
    } else if (bid < 72) {  // bvWo
      const int e = (bid - 64) * 128 + (tid >> 1);
      const int h = (tid & 1) * 512;
      float s = 0.f;
#pragma unroll 4
      for (int m = 0; m < 512; m++) s += bv[h + m] * Wo[(size_t)(h + m) * 1024 + e];
      s += __shfl_xor(s, 1);
      if ((tid & 1) == 0) bvWo[e] = s;
    }
    return;
  }
  // z == 0,1: transpose+convert Wq / Wk.
  const float* W = (z == 0) ? Wq : Wk;
  __bf16* D = Wt + (size_t)z * 1024 * 1024;
  __shared__ float T[64][65];
  const int r0 = blockIdx.y * 64, c0 = blockIdx.x * 64;
#pragma unroll
  for (int i = 0; i < 16; i++) {
    const int e = i * 256 + tid;
    const int r = e >> 6, c = e & 63;
    T[r][c] = W[(size_t)(r0 + r) * 1024 + c0 + c];
  }
  __syncthreads();
#pragma unroll
  for (int i = 0; i < 4; i++) {
    const int e = i * 256 + tid;        // 4 elems per thread
    const int rr = e >> 4;              // 0..63  (D row within tile)
    const int c4 = (e & 15) * 4;        // 0..60  (D col base)
    bf16x4 o;
#pragma unroll
    for (int j = 0; j < 4; j++) o[j] = (__bf16)T[c4 + j][rr];
    *(bf16x4*)&D[(size_t)(c0 + rr) * 1024 + r0 + c4] = o;
  }
}

// QKV' projection: C[8192 x 3072] = Xb @ B^T. Chunks: 0=Q(+bq), 1=K(+bk),
// 2=VWo(+bv@Wo) stored TRANSPOSED per batch (VWoT[e][s]). V is never
// materialized: VWo = X @ (Wv@Wo) + bv@Wo.  grid (24, 64), 256 thr.
// Epilogue C/D layout (m89): col = lane&15, row = (lane>>4)*4 + r.
__global__ __launch_bounds__(256) void qkv_k(
    const __bf16* __restrict__ Xb, const __bf16* __restrict__ Wt,
    const __bf16* __restrict__ MTb, const float* __restrict__ bq,
    const float* __restrict__ bk, const float* __restrict__ bvwo,
    __bf16* __restrict__ QK, __bf16* __restrict__ VWoT) {
  GEMM_PRE(4);
  const int m0 = blockIdx.y * 128, n0 = blockIdx.x * 128;
  const int chunk = n0 >> 10;  // 0=Q 1=K 2=VWo (block-uniform)
  const __bf16* Bbase = chunk < 2 ? Wt : MTb;
  const int n0l = chunk < 2 ? n0 : n0 - 2048;
  gemm_core<4>(Xb, Bbase, As, Bs, acc, m0, n0l, 1024, 1024, 1024, tid);
  if (chunk < 2) {
    const float* bp = chunk == 0 ? bq : bk;
#pragma unroll
    for (int mt = 0; mt < 4; mt++) {
      const int gmb = m0 + (w >> 1) * 64 + mt * 16 + quad * 4;
#pragma unroll
      for (int nt = 0; nt < 4; nt++) {
        const int gnl = (n0 + (w & 1) * 64 + nt * 16 + lo) & 1023;
        const float b_ = bp[gnl];
#pragma unroll
        for (int r = 0; r < 4; r++)
          QK[(size_t)chunk * MSH + (size_t)(gmb + r) * 1024 + gnl] =
              (__bf16)(acc[mt][nt][r] + b_);
      }
    }
  } else {
    const int bz = m0 >> 11;                        // batch
    const int sb = (m0 & 2047) + (w >> 1) * 64;     // local s base
#pragma unroll
    for (int mt = 0; mt < 4; mt++) {
      const int sl = sb + mt * 16 + quad * 4;
#pragma unroll
      for (int nt = 0; nt < 4; nt++) {
        const int e = (n0 + (w & 1) * 64 + nt * 16 + lo) & 1023;
        const float b_ = bvwo[e];
        bf16x4 pk;
#pragma unroll
        for (int r = 0; r < 4; r++) pk[r] = (__bf16)(acc[mt][nt][r] + b_);
        *(bf16x4*)(VWoT + (size_t)bz * SH + (size_t)e * 2048 + sl) = pk;
      }
    }
  }
}

// MID (exp only): E = exp(maskbit ? 1e-20 : QK^T/32) bf16 + rowsum atomics
// into L. grid (256, 1, 4) = 4 blocks/CU resident. XCD decode: xcd x owns
// by in [(x>>1)*4,+4) x bx in [(x&1)*8,+8).
__global__ __launch_bounds__(256) void mid_k(
    const __bf16* __restrict__ QK, __bf16* __restrict__ E,
    const unsigned* __restrict__ Pk, float* __restrict__ L) {
  GEMM_PRE(4);
  const int bz = blockIdx.z;
  const int sid = blockIdx.x;
  const int xcd = sid & 7, kk = sid >> 3;           // kk 0..31
  const int m0 = ((xcd >> 1) * 4 + (kk >> 3)) * 128;  // by 0..15
  const int n0 = ((xcd & 1) * 8 + (kk & 7)) * 128;    // bx 0..15
  gemm_core<4>(QK + bz * SH, QK + MSH + bz * SH, As, Bs, acc,
               m0, n0, 1024, 1024, 1024, tid);
  const unsigned* Pb = Pk + (size_t)bz * 131072;
#pragma unroll
  for (int mt = 0; mt < 4; mt++) {
    const int gmb = m0 + (w >> 1) * 64 + mt * 16 + quad * 4;
#pragma unroll
    for (int r = 0; r < 4; r++) {
      const int gm = gmb + r;
      float rowpart = 0.f;
#pragma unroll
      for (int nt = 0; nt < 4; nt++) {
        const int gn = n0 + (w & 1) * 64 + nt * 16 + lo;
        const unsigned wd = Pb[(size_t)gm * 64 + (gn >> 5)];
        float s = acc[mt][nt][r] * 0.03125f;
        if ((wd >> (gn & 31)) & 1u) s = 1e-20f;
        const float e = __expf(s);
        rowpart += e;
        E[(size_t)bz * SS + (size_t)gm * 2048 + gn] = (__bf16)e;
      }
      rowpart += __shfl_xor(rowpart, 1);
      rowpart += __shfl_xor(rowpart, 2);
      rowpart += __shfl_xor(rowpart, 4);
      rowpart += __shfl_xor(rowpart, 8);
      if (lo == 0) atomicAdd(&L[(size_t)bz * 2048 + gm], rowpart);
    }
  }
}

// CTX/OUT fused: out = (E @ VWoT^T) / L + bo -> fp32. 128x64 tiles (NB=2),
// grid (256,1,4) = 4 blocks/CU, XCD patch decode. (round-6 verified)
__global__ __launch_bounds__(256) void ctx_k(
    const __bf16* __restrict__ E, const __bf16* __restrict__ VWoT,
    const float* __restrict__ L, const float* __restrict__ bo,
    float* __restrict__ out) {
  GEMM_PRE(2);
  const int bz = blockIdx.z;
  const int sid = blockIdx.x;                 // 0..255
  const int xcd = sid & 7, k = sid >> 3;      // k 0..31
  const int p  = k >> 3;                      // patch 0..3 within XCD
  const int q  = k & 7;                       // 0..7 within patch
  const int py = (xcd >> 2) * 4 + p;          // 0..7
  const int px = xcd & 3;                     // 0..3
  const int m0 = (py * 2 + (q >> 2)) * 128;   // m-tile 0..15
  const int n0 = (px * 4 + (q & 3)) * 64;     // n-tile 0..15
  gemm_core<2>(E + (size_t)bz * SS, VWoT + (size_t)bz * SH, As, Bs, acc,
               m0, n0, 2048, 2048, 2048, tid);
#pragma unroll
  for (int mt = 0; mt < 4; mt++) {
    const int gmb = m0 + (w >> 1) * 64 + mt * 16 + quad * 4;
#pragma unroll
    for (int nt = 0; nt < 2; nt++) {
      const int gn = n0 + (w & 1) * 32 + nt * 16 + lo;
      const float bo_ = bo[gn];
#pragma unroll
      for (int r = 0; r < 4; r++) {
        const int gm = gmb + r;
        const float inv = 1.0f / L[(size_t)bz * 2048 + gm];
        out[((size_t)bz * 2048 + gm) * 1024 + gn] = acc[mt][nt][r] * inv + bo_;
      }
    }
  }
}

extern "C" void kernel_launch(void* const* d_in, const int* in_sizes, int n_in,
                              void* d_out, int out_size, void* d_ws, size_t ws_size,
                              hipStream_t stream) {
  (void)in_sizes; (void)n_in; (void)out_size; (void)ws_size;
  const int H = 1024;

  const float* X   = (const float*)d_in[0];
  const int*   msk = (const int*)d_in[1];
  const float* Wq  = (const float*)d_in[2];
  const float* bq  = (const float*)d_in[3];
  const float* Wk  = (const float*)d_in[4];
  const float* bk  = (const float*)d_in[5];
  const float* Wv  = (const float*)d_in[6];
  const float* bv  = (const float*)d_in[7];
  const float* Wo  = (const float*)d_in[8];
  const float* bo  = (const float*)d_in[9];
  float* out = (float*)d_out;

  // Workspace (~109 MB):
  //   Xb[16.8M] Wt[4.2M: Wq^T|Wk^T] MTb[2.1M] QK[33.6M] VWoT[16.8M]
  //   E[33.6M] L[32K] bvWo[4K] Pk[2.1M]
  char* ws = (char*)d_ws;
  __bf16* Xb   = (__bf16*)ws;
  __bf16* Wt   = Xb + (size_t)8192 * H;
  __bf16* MTb  = Wt + (size_t)2 * H * H;
  __bf16* QK   = MTb + (size_t)H * H;
  __bf16* VWoT = QK + (size_t)2 * 8192 * H;
  __bf16* E    = VWoT + (size_t)4 * H * 2048;
  float*  L    = (float*)(E + (size_t)4 * SS);
  float*  bvWo = L + 8192;
  unsigned* Pk = (unsigned*)(bvWo + 1024);

  dim3 blk(256);

  prep_k<<<dim3(16, 16, 8), blk, 0, stream>>>(X, Xb, Wq, Wk, Wv, Wo, bv,
                                              Wt, MTb, bvWo, L, msk, Pk);
  qkv_k<<<dim3(24, 64), blk, 0, stream>>>(Xb, Wt, MTb, bq, bk, bvWo, QK, VWoT);
  mid_k<<<dim3(256, 1, 4), blk, 0, stream>>>(QK, E, Pk, L);
  ctx_k<<<dim3(256, 1, 4), blk, 0, stream>>>(E, VWoT, L, bo, out);
}

// Round 9
// 351.451 us; speedup vs baseline: 1.2074x; 1.0331x over previous
//
#include <hip/hip_runtime.h>
#include <hip/hip_bf16.h>

typedef __bf16 bf16x8 __attribute__((ext_vector_type(8)));
typedef __bf16 bf16x4 __attribute__((ext_vector_type(4)));
typedef float  floatx4 __attribute__((ext_vector_type(4)));

#define SH  2097152ll  // per-batch plane: 2048*1024
#define MSH 8388608ll  // full Q/K plane: 8192*1024
#define SS  4194304ll  // per-batch score plane: 2048*2048

// Async global->LDS, 16 B per lane. LDS dest is wave-uniform base + lane*16.
#define GLOAD16(gp, lp)                                                        \
  __builtin_amdgcn_global_load_lds(                                            \
      (const __attribute__((address_space(1))) void*)(gp),                     \
      (__attribute__((address_space(3))) void*)(lp), 16, 0, 0)

// ---------------------------------------------------------------------------
// Verified bf16 core (rounds 0/5/6): 128 x (NB*32) x BK64, 256 thr = 4 waves.
// 32 KB LDS -> 4-5 blocks/CU; cross-block MFMA/staging overlap is the
// mechanism (qkv 29.9% MfmaUtil at 6/CU vs 21-24% for all 1-block/CU
// schedule variants). LDS XOR swizzle: chunk c of row r at physical c^(r&7);
// staging lane loads global chunk (lane&7)^(lane>>3).
// SQ_LDS_BANK_CONFLICT == 0 measured.
// ---------------------------------------------------------------------------
template <int NB>
__device__ __forceinline__ void gemm_core(
    const __bf16* __restrict__ A, const __bf16* __restrict__ B,
    __bf16* As, __bf16* Bs, floatx4 (&acc)[4][NB],
    int m0, int n0, int Kd, int lda, int ldb, int tid) {
  const int lane = tid & 63;
  const int w    = tid >> 6;
  const int lo   = lane & 15;
  const int quad = lane >> 4;
  const int lrow  = lane >> 3;
  const int lcol8 = ((lane & 7) ^ lrow) * 8;

  const __bf16* aptr = A + (size_t)(m0 + w * 32 + lrow) * lda + lcol8;
  const __bf16* bptr = B + (size_t)(n0 + w * (NB * 8) + lrow) * ldb + lcol8;
  __bf16* asl = As + (w * 32) * 64;
  __bf16* bsl = Bs + (w * (NB * 8)) * 64;

  const int x7 = lo & 7;

  for (int kk = 0; kk < Kd; kk += 64) {
#pragma unroll
    for (int i = 0; i < 4; i++)
      GLOAD16(aptr + (size_t)(i * 8) * lda + kk, asl + i * 8 * 64);
#pragma unroll
    for (int i = 0; i < NB; i++)
      GLOAD16(bptr + (size_t)(i * 8) * ldb + kk, bsl + i * 8 * 64);
    __syncthreads();
#pragma unroll
    for (int kq = 0; kq < 2; kq++) {
      const int pq = ((kq * 4 + quad) ^ x7) * 8;
      bf16x8 af[4], bfq[NB];
#pragma unroll
      for (int mt = 0; mt < 4; mt++)
        af[mt] = *(const bf16x8*)&As[((w >> 1) * 64 + mt * 16 + lo) * 64 + pq];
#pragma unroll
      for (int nt = 0; nt < NB; nt++)
        bfq[nt] = *(const bf16x8*)
            &Bs[((w & 1) * (NB * 16) + nt * 16 + lo) * 64 + pq];
#pragma unroll
      for (int mt = 0; mt < 4; mt++)
#pragma unroll
        for (int nt = 0; nt < NB; nt++)
          acc[mt][nt] = __builtin_amdgcn_mfma_f32_16x16x32_bf16(af[mt], bfq[nt], acc[mt][nt], 0, 0, 0);
    }
    __syncthreads();
  }
}

#define GEMM_PRE(NB)                                                           \
  __shared__ __bf16 As[128 * 64];                                              \
  __shared__ __bf16 Bs[(NB) * 32 * 64];                                        \
  const int tid = threadIdx.x;                                                 \
  floatx4 acc[4][NB];                                                          \
  _Pragma("unroll") for (int mt = 0; mt < 4; mt++)                             \
      _Pragma("unroll") for (int nt = 0; nt < (NB); nt++)                      \
          acc[mt][nt] = (floatx4){0.f, 0.f, 0.f, 0.f};                         \
  const int lane = tid & 63, w = tid >> 6, lo = lane & 15, quad = lane >> 4;   \
  (void)lo; (void)quad;

// ---------------------------------------------------------------------------
// fp32-direct staging (prep MT GEMM): convert fp32 global -> swizzled bf16
// LDS in registers. Same LDS layout as GLOAD16 staging. (rounds 7/8 verified)
// ---------------------------------------------------------------------------
__device__ __forceinline__ void stage_f32(const float* __restrict__ G,
                                          int row0, int kk, __bf16* Ls, int tid) {
  const int lane = tid & 63, w = tid >> 6;
  const int lrow = lane >> 3, lch = ((lane & 7) ^ lrow) * 8;
#pragma unroll
  for (int i = 0; i < 4; i++) {
    const float* p = G + (size_t)(row0 + w * 32 + i * 8 + lrow) * 1024 + kk + lch;
    float4 v0 = *(const float4*)p, v1 = *(const float4*)(p + 4);
    bf16x8 o;
    o[0] = (__bf16)v0.x; o[1] = (__bf16)v0.y; o[2] = (__bf16)v0.z; o[3] = (__bf16)v0.w;
    o[4] = (__bf16)v1.x; o[5] = (__bf16)v1.y; o[6] = (__bf16)v1.z; o[7] = (__bf16)v1.w;
    ((bf16x8*)Ls)[(w * 32 + i * 8) * 8 + lane] = o;
  }
}

// Transpose-stage: source G fp32 [k][e] row-major; tile = 128 e-rows x 64 k.
// Logical k-chunk c of row e written at physical chunk c^(e&7).
__device__ __forceinline__ void stage_f32_t(const float* __restrict__ G,
                                            int e0, int kk, __bf16* Ls, int tid) {
  const int e  = tid & 127;
  const int c2 = tid >> 7;   // 0..1
#pragma unroll
  for (int q = 0; q < 4; q++) {
    const int c = c2 * 4 + q;
    bf16x8 o;
#pragma unroll
    for (int i = 0; i < 8; i++)
      o[i] = (__bf16)G[(size_t)(kk + c * 8 + i) * 1024 + e0 + e];
    *(bf16x8*)((char*)Ls + e * 128 + ((c ^ (e & 7)) * 16)) = o;
  }
}

// C[m][n] = sum_k A^T-staged[m][k] * B[n][k]  (A from fp32 cols, B fp32 rows)
__device__ __forceinline__ void gemm_f32t(
    const float* __restrict__ Ag, const float* __restrict__ Bg,
    __bf16* As, __bf16* Bs, floatx4 (&acc)[4][4], int m0, int n0, int tid) {
  const int lane = tid & 63, w = tid >> 6;
  const int lo = lane & 15, quad = lane >> 4;
  const int x7 = lo & 7;
  for (int kk = 0; kk < 1024; kk += 64) {
    stage_f32_t(Ag, m0, kk, As, tid);
    stage_f32(Bg, n0, kk, Bs, tid);
    __syncthreads();
#pragma unroll
    for (int kq = 0; kq < 2; kq++) {
      const int pq = ((kq * 4 + quad) ^ x7) * 8;
      bf16x8 af[4], bfq[4];
#pragma unroll
      for (int mt = 0; mt < 4; mt++)
        af[mt] = *(const bf16x8*)&As[((w >> 1) * 64 + mt * 16 + lo) * 64 + pq];
#pragma unroll
      for (int nt = 0; nt < 4; nt++)
        bfq[nt] = *(const bf16x8*)&Bs[((w & 1) * 64 + nt * 16 + lo) * 64 + pq];
#pragma unroll
      for (int mt = 0; mt < 4; mt++)
#pragma unroll
        for (int nt = 0; nt < 4; nt++)
          acc[mt][nt] = __builtin_amdgcn_mfma_f32_16x16x32_bf16(af[mt], bfq[nt], acc[mt][nt], 0, 0, 0);
    }
    __syncthreads();
  }
}

// ---------------------------------------------------------------------------
// PREP, grid (16,16,8). Z-ORDER = DISPATCH ORDER (x fastest, z slowest):
//  z=0    : THE SLOW PLANE FIRST (round-8 lesson: at z=7 these 72 blocks ran
//           as a lone tail after all memory blocks -> prep 88us at 11% occ).
//           bid 0..63  : MTb[e][d] = (Wv@Wo)[d][e] from RAW fp32.
//           bid 64..71 : bvWo = bv @ Wo.   (bid 72..255 exit)
//  z=1,2  : transpose+convert Wq,Wk (fp32 K x N) -> bf16 N x K plane of Wt.
//  z=3    : X fp32 -> bf16; zero L (first 32 blocks).
//  z=4..7 : mask pack -> bitmask Pk (quarter per plane).
// ---------------------------------------------------------------------------
__global__ __launch_bounds__(256) void prep_k(
    const float* __restrict__ X, __bf16* __restrict__ Xb,
    const float* __restrict__ Wq, const float* __restrict__ Wk,
    const float* __restrict__ Wv, const float* __restrict__ Wo,
    const float* __restrict__ bv, __bf16* __restrict__ Wt,
    __bf16* __restrict__ MTb, float* __restrict__ bvWo,
    float* __restrict__ L, const int* __restrict__ mask,
    unsigned* __restrict__ Pk) {
  __shared__ __bf16 As[128 * 64];
  __shared__ __bf16 Bs[128 * 64];
  const int z = blockIdx.z;
  const int tid = threadIdx.x;
  const int bid = blockIdx.y * 16 + blockIdx.x;  // 0..255
  if (z == 0) {
    if (bid < 64) {  // MT tiles
      const int m0 = (bid >> 3) * 128, n0 = (bid & 7) * 128;
      floatx4 acc[4][4];
#pragma unroll
      for (int mt = 0; mt < 4; mt++)
#pragma unroll
        for (int nt = 0; nt < 4; nt++) acc[mt][nt] = (floatx4){0.f, 0.f, 0.f, 0.f};
      gemm_f32t(Wo, Wv, As, Bs, acc, m0, n0, tid);  // MT[e][d]
      const int lane = tid & 63, w = tid >> 6, lo = lane & 15, quad = lane >> 4;
#pragma unroll
      for (int mt = 0; mt < 4; mt++) {
        const int ge = m0 + (w >> 1) * 64 + mt * 16 + quad * 4;
#pragma unroll
        for (int nt = 0; nt < 4; nt++) {
          const int gd = n0 + (w & 1) * 64 + nt * 16 + lo;
#pragma unroll
          for (int r = 0; r < 4; r++)
            MTb[(size_t)(ge + r) * 1024 + gd] = (__bf16)acc[mt][nt][r];
        }
      }
    } else if (bid < 72) {  // bvWo
      const int e = (bid - 64) * 128 + (tid >> 1);
      const int h = (tid & 1) * 512;
      float s = 0.f;
#pragma unroll 4
      for (int m = 0; m < 512; m++) s += bv[h + m] * Wo[(size_t)(h + m) * 1024 + e];
      s += __shfl_xor(s, 1);
      if ((tid & 1) == 0) bvWo[e] = s;
    }
    return;
  }
  if (z == 3) {
    if (bid < 32) L[bid * 256 + tid] = 0.f;
#pragma unroll
    for (int k = 0; k < 32; k++) {
      const size_t i = (size_t)(bid * 256 + tid) + (size_t)k * 65536;
      const float4 v = ((const float4*)X)[i];
      bf16x4 o;
      o[0] = (__bf16)v.x; o[1] = (__bf16)v.y; o[2] = (__bf16)v.z; o[3] = (__bf16)v.w;
      ((bf16x4*)Xb)[i] = o;
    }
    return;
  }
  if (z >= 4) {
    const int base = (z - 4) * 131072;  // u32 words per quarter
#pragma unroll
    for (int k = 0; k < 2; k++) {
      const int idx = base + bid * 512 + k * 256 + tid;
      const int4* m4 = (const int4*)(mask + (size_t)idx * 32);
      unsigned bits = 0;
#pragma unroll
      for (int q = 0; q < 8; q++) {
        int4 v = m4[q];
        bits |= (v.x != 0 ? 1u : 0u) << (q * 4);
        bits |= (v.y != 0 ? 1u : 0u) << (q * 4 + 1);
        bits |= (v.z != 0 ? 1u : 0u) << (q * 4 + 2);
        bits |= (v.w != 0 ? 1u : 0u) << (q * 4 + 3);
      }
      Pk[idx] = bits;
    }
    return;
  }
  // z == 1,2: transpose+convert Wq / Wk.
  const float* W = (z == 1) ? Wq : Wk;
  __bf16* D = Wt + (size_t)(z - 1) * 1024 * 1024;
  __shared__ float T[64][65];
  const int r0 = blockIdx.y * 64, c0 = blockIdx.x * 64;
#pragma unroll
  for (int i = 0; i < 16; i++) {
    const int e = i * 256 + tid;
    const int r = e >> 6, c = e & 63;
    T[r][c] = W[(size_t)(r0 + r) * 1024 + c0 + c];
  }
  __syncthreads();
#pragma unroll
  for (int i = 0; i < 4; i++) {
    const int e = i * 256 + tid;        // 4 elems per thread
    const int rr = e >> 4;              // 0..63  (D row within tile)
    const int c4 = (e & 15) * 4;        // 0..60  (D col base)
    bf16x4 o;
#pragma unroll
    for (int j = 0; j < 4; j++) o[j] = (__bf16)T[c4 + j][rr];
    *(bf16x4*)&D[(size_t)(c0 + rr) * 1024 + r0 + c4] = o;
  }
}

// QKV' projection: C[8192 x 3072] = Xb @ B^T. Chunks: 0=Q(+bq), 1=K(+bk),
// 2=VWo(+bv@Wo) stored TRANSPOSED per batch (VWoT[e][s]). V is never
// materialized: VWo = X @ (Wv@Wo) + bv@Wo.  grid (24, 64), 256 thr.
// Epilogue C/D layout (m89): col = lane&15, row = (lane>>4)*4 + r.
__global__ __launch_bounds__(256) void qkv_k(
    const __bf16* __restrict__ Xb, const __bf16* __restrict__ Wt,
    const __bf16* __restrict__ MTb, const float* __restrict__ bq,
    const float* __restrict__ bk, const float* __restrict__ bvwo,
    __bf16* __restrict__ QK, __bf16* __restrict__ VWoT) {
  GEMM_PRE(4);
  const int m0 = blockIdx.y * 128, n0 = blockIdx.x * 128;
  const int chunk = n0 >> 10;  // 0=Q 1=K 2=VWo (block-uniform)
  const __bf16* Bbase = chunk < 2 ? Wt : MTb;
  const int n0l = chunk < 2 ? n0 : n0 - 2048;
  gemm_core<4>(Xb, Bbase, As, Bs, acc, m0, n0l, 1024, 1024, 1024, tid);
  if (chunk < 2) {
    const float* bp = chunk == 0 ? bq : bk;
#pragma unroll
    for (int mt = 0; mt < 4; mt++) {
      const int gmb = m0 + (w >> 1) * 64 + mt * 16 + quad * 4;
#pragma unroll
      for (int nt = 0; nt < 4; nt++) {
        const int gnl = (n0 + (w & 1) * 64 + nt * 16 + lo) & 1023;
        const float b_ = bp[gnl];
#pragma unroll
        for (int r = 0; r < 4; r++)
          QK[(size_t)chunk * MSH + (size_t)(gmb + r) * 1024 + gnl] =
              (__bf16)(acc[mt][nt][r] + b_);
      }
    }
  } else {
    const int bz = m0 >> 11;                        // batch
    const int sb = (m0 & 2047) + (w >> 1) * 64;     // local s base
#pragma unroll
    for (int mt = 0; mt < 4; mt++) {
      const int sl = sb + mt * 16 + quad * 4;
#pragma unroll
      for (int nt = 0; nt < 4; nt++) {
        const int e = (n0 + (w & 1) * 64 + nt * 16 + lo) & 1023;
        const float b_ = bvwo[e];
        bf16x4 pk;
#pragma unroll
        for (int r = 0; r < 4; r++) pk[r] = (__bf16)(acc[mt][nt][r] + b_);
        *(bf16x4*)(VWoT + (size_t)bz * SH + (size_t)e * 2048 + sl) = pk;
      }
    }
  }
}

// MID (exp only): E = exp(maskbit ? 1e-20 : QK^T/32) bf16 + rowsum atomics
// into L. grid (256, 1, 4) = 4 blocks/CU resident. XCD decode: xcd x owns
// by in [(x>>1)*4,+4) x bx in [(x&1)*8,+8).
__global__ __launch_bounds__(256) void mid_k(
    const __bf16* __restrict__ QK, __bf16* __restrict__ E,
    const unsigned* __restrict__ Pk, float* __restrict__ L) {
  GEMM_PRE(4);
  const int bz = blockIdx.z;
  const int sid = blockIdx.x;
  const int xcd = sid & 7, kk = sid >> 3;           // kk 0..31
  const int m0 = ((xcd >> 1) * 4 + (kk >> 3)) * 128;  // by 0..15
  const int n0 = ((xcd & 1) * 8 + (kk & 7)) * 128;    // bx 0..15
  gemm_core<4>(QK + bz * SH, QK + MSH + bz * SH, As, Bs, acc,
               m0, n0, 1024, 1024, 1024, tid);
  const unsigned* Pb = Pk + (size_t)bz * 131072;
#pragma unroll
  for (int mt = 0; mt < 4; mt++) {
    const int gmb = m0 + (w >> 1) * 64 + mt * 16 + quad * 4;
#pragma unroll
    for (int r = 0; r < 4; r++) {
      const int gm = gmb + r;
      float rowpart = 0.f;
#pragma unroll
      for (int nt = 0; nt < 4; nt++) {
        const int gn = n0 + (w & 1) * 64 + nt * 16 + lo;
        const unsigned wd = Pb[(size_t)gm * 64 + (gn >> 5)];
        float s = acc[mt][nt][r] * 0.03125f;
        if ((wd >> (gn & 31)) & 1u) s = 1e-20f;
        const float e = __expf(s);
        rowpart += e;
        E[(size_t)bz * SS + (size_t)gm * 2048 + gn] = (__bf16)e;
      }
      rowpart += __shfl_xor(rowpart, 1);
      rowpart += __shfl_xor(rowpart, 2);
      rowpart += __shfl_xor(rowpart, 4);
      rowpart += __shfl_xor(rowpart, 8);
      if (lo == 0) atomicAdd(&L[(size_t)bz * 2048 + gm], rowpart);
    }
  }
}

// CTX/OUT fused: out = (E @ VWoT^T) / L + bo -> fp32. 128x64 tiles (NB=2),
// grid (256,1,4) = 4 blocks/CU, XCD patch decode. (round-6 verified)
__global__ __launch_bounds__(256) void ctx_k(
    const __bf16* __restrict__ E, const __bf16* __restrict__ VWoT,
    const float* __restrict__ L, const float* __restrict__ bo,
    float* __restrict__ out) {
  GEMM_PRE(2);
  const int bz = blockIdx.z;
  const int sid = blockIdx.x;                 // 0..255
  const int xcd = sid & 7, k = sid >> 3;      // k 0..31
  const int p  = k >> 3;                      // patch 0..3 within XCD
  const int q  = k & 7;                       // 0..7 within patch
  const int py = (xcd >> 2) * 4 + p;          // 0..7
  const int px = xcd & 3;                     // 0..3
  const int m0 = (py * 2 + (q >> 2)) * 128;   // m-tile 0..15
  const int n0 = (px * 4 + (q & 3)) * 64;     // n-tile 0..15
  gemm_core<2>(E + (size_t)bz * SS, VWoT + (size_t)bz * SH, As, Bs, acc,
               m0, n0, 2048, 2048, 2048, tid);
#pragma unroll
  for (int mt = 0; mt < 4; mt++) {
    const int gmb = m0 + (w >> 1) * 64 + mt * 16 + quad * 4;
#pragma unroll
    for (int nt = 0; nt < 2; nt++) {
      const int gn = n0 + (w & 1) * 32 + nt * 16 + lo;
      const float bo_ = bo[gn];
#pragma unroll
      for (int r = 0; r < 4; r++) {
        const int gm = gmb + r;
        const float inv = 1.0f / L[(size_t)bz * 2048 + gm];
        out[((size_t)bz * 2048 + gm) * 1024 + gn] = acc[mt][nt][r] * inv + bo_;
      }
    }
  }
}

extern "C" void kernel_launch(void* const* d_in, const int* in_sizes, int n_in,
                              void* d_out, int out_size, void* d_ws, size_t ws_size,
                              hipStream_t stream) {
  (void)in_sizes; (void)n_in; (void)out_size; (void)ws_size;
  const int H = 1024;

  const float* X   = (const float*)d_in[0];
  const int*   msk = (const int*)d_in[1];
  const float* Wq  = (const float*)d_in[2];
  const float* bq  = (const float*)d_in[3];
  const float* Wk  = (const float*)d_in[4];
  const float* bk  = (const float*)d_in[5];
  const float* Wv  = (const float*)d_in[6];
  const float* bv  = (const float*)d_in[7];
  const float* Wo  = (const float*)d_in[8];
  const float* bo  = (const float*)d_in[9];
  float* out = (float*)d_out;

  // Workspace (~109 MB):
  //   Xb[16.8M] Wt[4.2M: Wq^T|Wk^T] MTb[2.1M] QK[33.6M] VWoT[16.8M]
  //   E[33.6M] L[32K] bvWo[4K] Pk[2.1M]
  char* ws = (char*)d_ws;
  __bf16* Xb   = (__bf16*)ws;
  __bf16* Wt   = Xb + (size_t)8192 * H;
  __bf16* MTb  = Wt + (size_t)2 * H * H;
  __bf16* QK   = MTb + (size_t)H * H;
  __bf16* VWoT = QK + (size_t)2 * 8192 * H;
  __bf16* E    = VWoT + (size_t)4 * H * 2048;
  float*  L    = (float*)(E + (size_t)4 * SS);
  float*  bvWo = L + 8192;
  unsigned* Pk = (unsigned*)(bvWo + 1024);

  dim3 blk(256);

  prep_k<<<dim3(16, 16, 8), blk, 0, stream>>>(X, Xb, Wq, Wk, Wv, Wo, bv,
                                              Wt, MTb, bvWo, L, msk, Pk);
  qkv_k<<<dim3(24, 64), blk, 0, stream>>>(Xb, Wt, MTb, bq, bk, bvWo, QK, VWoT);
  mid_k<<<dim3(256, 1, 4), blk, 0, stream>>>(QK, E, Pk, L);
  ctx_k<<<dim3(256, 1, 4), blk, 0, stream>>>(E, VWoT, L, bo, out);
}